// Round 1
// baseline (590.866 us; speedup 1.0000x reference)
//
#include <hip/hip_runtime.h>
#include <math.h>

#define NB 512
#define NH 1024
#define NS 1024
#define ND 128
#define NK 32

// ---------------- Kernel 1: per-batch compute (one block per batch) --------
__global__ __launch_bounds__(256) void compute_kernel(
    const float* __restrict__ latent,      // [B,H]
    const float* __restrict__ memory,      // [B,S,D]
    const float* __restrict__ rq_w,        // [H,D]
    const float* __restrict__ rq_b,        // [D]
    const float* __restrict__ mem_key,     // [S,D]
    const float* __restrict__ wg_w,        // [H+D]
    const float* __restrict__ wg_b,        // [1]
    const float* __restrict__ dmd_w,       // [H+D]
    const float* __restrict__ dmd_b,       // [1]
    const float* __restrict__ ph_w,        // [H]
    const float* __restrict__ ph_b,        // [1]
    const float* __restrict__ wv_w,        // [H,D]
    const float* __restrict__ wv_b,        // [D]
    float* __restrict__ out_read,          // [B,D]
    float* __restrict__ out_wts,           // [B,S]
    float* __restrict__ gates,             // ws [B]
    float* __restrict__ valw)              // ws [B,D]
{
  const int b   = blockIdx.x;
  const int tid = threadIdx.x;

  __shared__ float lat[NH];     // 4 KB
  __shared__ float lg[NS];      // 4 KB
  __shared__ float qv[ND];
  __shared__ float part[256];
  __shared__ float rd[ND];
  __shared__ float tv[NK];
  __shared__ int   ti[NK];
  __shared__ float wk[NK];
  __shared__ float redv[4];
  __shared__ int   redi[4];
  __shared__ float scal[4];

  // ---- load latent row into LDS ----
  for (int h = tid; h < NH; h += 256) lat[h] = latent[(size_t)b * NH + h];
  __syncthreads();

  // ---- query = lat @ rq_w + rq_b  (split-K over 2 halves, 256 threads) ----
  {
    const int d = tid & 127, p = tid >> 7;
    float acc = 0.f;
    const float* W = rq_w + (size_t)p * 512 * ND + d;
    const float* L = lat + p * 512;
    #pragma unroll 8
    for (int h = 0; h < 512; ++h) acc += L[h] * W[(size_t)h * ND];
    part[tid] = acc;
  }
  __syncthreads();
  if (tid < ND) qv[tid] = part[tid] + part[tid + 128] + rq_b[tid];
  __syncthreads();

  // ---- logits[s] = qv . mem_key[s]  (4 slots per thread, float4) ----
  {
    const float4* q4 = (const float4*)qv;
    for (int j = 0; j < 4; ++j) {
      int s = tid + j * 256;
      const float4* k4 = (const float4*)(mem_key + (size_t)s * ND);
      float acc = 0.f;
      #pragma unroll
      for (int i = 0; i < ND / 4; ++i) {
        float4 kv = k4[i]; float4 qq = q4[i];
        acc += kv.x * qq.x + kv.y * qq.y + kv.z * qq.z + kv.w * qq.w;
      }
      lg[s] = acc;
    }
  }
  __syncthreads();

  // ---- top-32 of logits via 32x iterative block argmax ----
  const float NEGINF = -3.0e38f;
  for (int kk = 0; kk < NK; ++kk) {
    float best = NEGINF; int bi = 0;
    #pragma unroll
    for (int j = 0; j < 4; ++j) {
      int s = tid + j * 256;
      float v = lg[s];
      if (v > best) { best = v; bi = s; }
    }
    #pragma unroll
    for (int off = 32; off > 0; off >>= 1) {
      float ov = __shfl_down(best, off);
      int   oi = __shfl_down(bi,   off);
      if (ov > best) { best = ov; bi = oi; }
    }
    if ((tid & 63) == 0) { redv[tid >> 6] = best; redi[tid >> 6] = bi; }
    __syncthreads();
    if (tid == 0) {
      float bv = redv[0]; int bb = redi[0];
      #pragma unroll
      for (int w = 1; w < 4; ++w) if (redv[w] > bv) { bv = redv[w]; bb = redi[w]; }
      tv[kk] = bv; ti[kk] = bb; lg[bb] = NEGINF;
    }
    __syncthreads();
  }

  // ---- masked renormalized weights = softmax over the 32 selected logits ----
  // tv[0] is the max (iterative argmax extracts in descending order)
  if (tid < 64) {
    float e = (tid < NK) ? expf(tv[tid] - tv[0]) : 0.f;
    if (tid < NK) wk[tid] = e;
    float s = e;
    #pragma unroll
    for (int off = 32; off > 0; off >>= 1) s += __shfl_down(s, off);
    if (tid == 0) scal[0] = s;
  }
  __syncthreads();
  if (tid < NK) wk[tid] = wk[tid] / scal[0];
  __syncthreads();

  // ---- read = sum_k wk[k] * memory[b, ti[k], :]  (only 32 rows needed) ----
  if (tid < ND) {
    float r = 0.f;
    const float* mb = memory + (size_t)b * NS * ND;
    #pragma unroll 4
    for (int k = 0; k < NK; ++k) r += wk[k] * mb[(size_t)ti[k] * ND + tid];
    rd[tid] = r;
    out_read[(size_t)b * ND + tid] = r;
  }
  __syncthreads();

  // ---- gate scalars: 3 dot products + pointwise ----
  {
    float p1 = 0.f, p2 = 0.f, p3 = 0.f;
    for (int h = tid; h < NH; h += 256) {
      float l = lat[h];
      p1 += l * wg_w[h]; p2 += l * dmd_w[h]; p3 += l * ph_w[h];
    }
    if (tid < ND) {
      float r = rd[tid];
      p1 += r * wg_w[NH + tid]; p2 += r * dmd_w[NH + tid];
    }
    #pragma unroll
    for (int off = 32; off > 0; off >>= 1) {
      p1 += __shfl_down(p1, off);
      p2 += __shfl_down(p2, off);
      p3 += __shfl_down(p3, off);
    }
    if ((tid & 63) == 0) { int w = tid >> 6; redv[w] = p1; part[w] = p2; part[8 + w] = p3; }
    __syncthreads();
    if (tid == 0) {
      float z1 = redv[0] + redv[1] + redv[2] + redv[3] + wg_b[0];
      float z2 = part[0] + part[1] + part[2] + part[3] + dmd_b[0];
      float z3 = part[8] + part[9] + part[10] + part[11] + ph_b[0];
      float g  = 1.f / (1.f + expf(-z1));
      float dm = tanhf(z2);
      g = g * (0.75f + 0.25f * (dm + 1.f));
      g = fminf(fmaxf(g, 0.f), 1.f);
      g = g * (0.5f * (1.f + cosf(z3)));
      scal[1] = g;
      gates[b] = g;
    }
    __syncthreads();
  }

  // ---- value = lat @ wv_w + wv_b ----
  {
    const int d = tid & 127, p = tid >> 7;
    float acc = 0.f;
    const float* W = wv_w + (size_t)p * 512 * ND + d;
    const float* L = lat + p * 512;
    #pragma unroll 8
    for (int h = 0; h < 512; ++h) acc += L[h] * W[(size_t)h * ND];
    part[tid] = acc;
  }
  __syncthreads();
  if (tid < ND) valw[(size_t)b * ND + tid] = part[tid] + part[tid + 128] + wv_b[tid];

  // ---- weights output: zeros except the 32 selected ----
  for (int j = 0; j < 4; ++j) {
    int s = tid + j * 256;
    float w = 0.f;
    #pragma unroll
    for (int t = 0; t < NK; ++t) if (ti[t] == s) w = wk[t];
    out_wts[(size_t)b * NS + s] = w;
  }
}

// ---------------- Kernel 2: bulk copy + sparse blend -----------------------
__global__ __launch_bounds__(256) void copy_blend_kernel(
    const float* __restrict__ memory,   // [B,S,D]
    const float* __restrict__ wts,      // [B,S] (already written by K1)
    const float* __restrict__ gates,    // [B]
    const float* __restrict__ valw,     // [B,D]
    float* __restrict__ out_mem)        // [B,S,D]
{
  const long long total4 = (long long)NB * NS * ND / 4;   // 16,777,216 float4
  const long long stride = (long long)gridDim.x * blockDim.x;
  for (long long i = (long long)blockIdx.x * blockDim.x + threadIdx.x;
       i < total4; i += stride) {
    long long e = i << 2;                 // element index
    int row = (int)(e >> 7);              // b*S + s
    float4 m = ((const float4*)memory)[i];
    float4 o = m;
    float w = wts[row];
    if (w != 0.f) {
      int b  = row >> 10;
      float g = gates[b] * w;
      const float4 v = *(const float4*)(valw + ((size_t)b << 7) + (e & 127));
      o.x = m.x + g * (v.x - m.x);
      o.y = m.y + g * (v.y - m.y);
      o.z = m.z + g * (v.z - m.z);
      o.w = m.w + g * (v.w - m.w);
    }
    ((float4*)out_mem)[i] = o;
  }
}

extern "C" void kernel_launch(void* const* d_in, const int* in_sizes, int n_in,
                              void* d_out, int out_size, void* d_ws, size_t ws_size,
                              hipStream_t stream) {
  const float* latent  = (const float*)d_in[0];
  const float* memory  = (const float*)d_in[1];
  const float* rq_w    = (const float*)d_in[2];
  const float* rq_b    = (const float*)d_in[3];
  const float* mem_key = (const float*)d_in[4];
  const float* wg_w    = (const float*)d_in[5];
  const float* wg_b    = (const float*)d_in[6];
  const float* dmd_w   = (const float*)d_in[7];
  const float* dmd_b   = (const float*)d_in[8];
  const float* ph_w    = (const float*)d_in[9];
  const float* ph_b    = (const float*)d_in[10];
  const float* wv_w    = (const float*)d_in[11];
  const float* wv_b    = (const float*)d_in[12];

  float* out_read = (float*)d_out;                          // [B,D]
  float* out_mem  = out_read + (size_t)NB * ND;             // [B,S,D]
  float* out_wts  = out_mem + (size_t)NB * NS * ND;         // [B,S]

  float* gates = (float*)d_ws;                              // [B]
  float* valw  = gates + 512;                               // [B,D] (16B-aligned)

  compute_kernel<<<NB, 256, 0, stream>>>(
      latent, memory, rq_w, rq_b, mem_key, wg_w, wg_b, dmd_w, dmd_b,
      ph_w, ph_b, wv_w, wv_b, out_read, out_wts, gates, valw);

  copy_blend_kernel<<<8192, 256, 0, stream>>>(memory, out_wts, gates, valw, out_mem);
}

// Round 3
// 548.108 us; speedup vs baseline: 1.0780x; 1.0780x over previous
//
#include <hip/hip_runtime.h>
#include <math.h>

#define NB 512
#define NH 1024
#define NS 1024
#define ND 128
#define NK 32

typedef float fx4 __attribute__((ext_vector_type(4)));

// ---------------- Kernel 1: per-batch compute, 512 threads -----------------
// Top-k is done with per-wave register argmax (no barriers in the loop),
// then a single-wave merge of the 8 sorted 32-lists.
__global__ __launch_bounds__(512) void compute_kernel(
    const float* __restrict__ latent,      // [B,H]
    const float* __restrict__ memory,      // [B,S,D]
    const float* __restrict__ rq_w,        // [H,D]
    const float* __restrict__ rq_b,        // [D]
    const float* __restrict__ mem_key,     // [S,D]
    const float* __restrict__ wg_w,        // [H+D]
    const float* __restrict__ wg_b,        // [1]
    const float* __restrict__ dmd_w,       // [H+D]
    const float* __restrict__ dmd_b,       // [1]
    const float* __restrict__ ph_w,        // [H]
    const float* __restrict__ ph_b,        // [1]
    const float* __restrict__ wv_w,        // [H,D]
    const float* __restrict__ wv_b,        // [D]
    float* __restrict__ out_read,          // [B,D]
    float* __restrict__ out_wts,           // [B,S]
    float* __restrict__ gw_out,            // ws [B,S]  gate-scaled weights
    float* __restrict__ valw)              // ws [B,D]
{
  const int b    = blockIdx.x;
  const int tid  = threadIdx.x;
  const int lane = tid & 63;
  const int wv   = tid >> 6;               // wave id, 0..7

  __shared__ float lat[NH];                // 4 KB
  __shared__ float wfull[NS];              // 4 KB
  __shared__ float part[512];              // 2 KB
  __shared__ float qv[ND];
  __shared__ float rd[ND];
  __shared__ float tvw[256];               // 8 waves x 32 candidates
  __shared__ int   tiw[256];
  __shared__ float wkL[NK];
  __shared__ int   tiL[NK];
  __shared__ float gred[24];
  __shared__ float scal[2];

  // ---- A: latent row into LDS (2 elems/thread) ----
  lat[tid]       = latent[(size_t)b * NH + tid];
  lat[tid + 512] = latent[(size_t)b * NH + tid + 512];
  __syncthreads();

  // ---- B: query = lat @ rq_w + rq_b (split-4 over H) ----
  {
    const int d = tid & 127, p = tid >> 7;
    const float* W = rq_w + (size_t)(p * 256) * ND + d;
    const float* L = lat + p * 256;
    float acc = 0.f;
    #pragma unroll 8
    for (int h = 0; h < 256; ++h) acc = fmaf(L[h], W[(size_t)h * ND], acc);
    part[tid] = acc;
  }
  __syncthreads();
  if (tid < ND)
    qv[tid] = part[tid] + part[tid + 128] + part[tid + 256] + part[tid + 384] + rq_b[tid];
  __syncthreads();

  // ---- D: logits, 2 slots per thread (s = tid, tid+512), kept in regs ----
  float r0 = 0.f, r1 = 0.f;
  {
    const float4* q4 = (const float4*)qv;
    const float4* k0 = (const float4*)(mem_key + (size_t)tid * ND);
    const float4* k1 = (const float4*)(mem_key + (size_t)(tid + 512) * ND);
    #pragma unroll 8
    for (int i = 0; i < ND / 4; ++i) {
      float4 q = q4[i];
      float4 x = k0[i];
      float4 y = k1[i];
      r0 += q.x * x.x + q.y * x.y + q.z * x.z + q.w * x.w;
      r1 += q.x * y.x + q.y * y.y + q.z * y.z + q.w * y.w;
    }
  }

  // ---- E: per-wave top-32 via register/shuffle argmax (no barriers) ----
  const float NEGINF = -3.0e38f;
  {
    const int s0 = tid, s1 = tid + 512;
    float v0 = r0, v1 = r1;
    for (int kk = 0; kk < NK; ++kk) {
      float best; int bi;
      if (v0 >= v1) { best = v0; bi = s0; } else { best = v1; bi = s1; }
      #pragma unroll
      for (int off = 1; off < 64; off <<= 1) {
        float ov = __shfl_xor(best, off);
        int   oi = __shfl_xor(bi, off);
        if (ov > best || (ov == best && oi < bi)) { best = ov; bi = oi; }
      }
      if (lane == 0) { tvw[(wv << 5) + kk] = best; tiw[(wv << 5) + kk] = bi; }
      if (bi == s0) v0 = NEGINF;
      if (bi == s1) v1 = NEGINF;
    }
  }
  // zero wfull while waves finish top-k (no conflict with merge)
  wfull[tid] = 0.f; wfull[tid + 512] = 0.f;
  __syncthreads();

  // ---- F: wave 0 merges 8x32 sorted lists -> global top-32 + softmax ----
  float selv = NEGINF; int seli = -1; float wkreg = 0.f;
  if (wv == 0) {
    float m0 = tvw[lane], m1 = tvw[lane + 64], m2 = tvw[lane + 128], m3 = tvw[lane + 192];
    int   i0 = tiw[lane], i1 = tiw[lane + 64], i2 = tiw[lane + 128], i3 = tiw[lane + 192];
    for (int kk = 0; kk < NK; ++kk) {
      float best = m0; int bi = i0;
      if (m1 > best || (m1 == best && i1 < bi)) { best = m1; bi = i1; }
      if (m2 > best || (m2 == best && i2 < bi)) { best = m2; bi = i2; }
      if (m3 > best || (m3 == best && i3 < bi)) { best = m3; bi = i3; }
      #pragma unroll
      for (int off = 1; off < 64; off <<= 1) {
        float ov = __shfl_xor(best, off);
        int   oi = __shfl_xor(bi, off);
        if (ov > best || (ov == best && oi < bi)) { best = ov; bi = oi; }
      }
      if (kk == lane) { selv = best; seli = bi; }
      if (bi == i0) m0 = NEGINF;
      if (bi == i1) m1 = NEGINF;
      if (bi == i2) m2 = NEGINF;
      if (bi == i3) m3 = NEGINF;
    }
    // softmax over the 32 selected logits (== masked-renormalized weights)
    float maxv = __shfl(selv, 0);           // kk=0 extraction is the global max
    float e = (lane < NK) ? expf(selv - maxv) : 0.f;
    float s = e;
    #pragma unroll
    for (int off = 1; off < 64; off <<= 1) s += __shfl_xor(s, off);
    wkreg = e / s;
    if (lane < NK) { wkL[lane] = wkreg; tiL[lane] = seli; }
  }
  __syncthreads();

  // ---- G: scatter weights into wfull; gather read vector (split-4 over k) ----
  if (wv == 0 && lane < NK) wfull[seli] = wkreg;
  {
    const int d = tid & 127, p = tid >> 7;
    const float* mb = memory + (size_t)b * NS * ND;
    float racc = 0.f;
    #pragma unroll
    for (int k = p * 8; k < p * 8 + 8; ++k)
      racc = fmaf(wkL[k], mb[(size_t)tiL[k] * ND + d], racc);
    part[tid] = racc;
  }
  __syncthreads();
  if (tid < ND) {
    float r = part[tid] + part[tid + 128] + part[tid + 256] + part[tid + 384];
    rd[tid] = r;
    out_read[(size_t)b * ND + tid] = r;
  }
  __syncthreads();

  // ---- I1: gate dot partials + value GEMV partials ----
  {
    float l0 = lat[tid], l1 = lat[tid + 512];
    float p1 = l0 * wg_w[tid]  + l1 * wg_w[tid + 512];
    float p2 = l0 * dmd_w[tid] + l1 * dmd_w[tid + 512];
    float p3 = l0 * ph_w[tid]  + l1 * ph_w[tid + 512];
    if (tid < ND) {
      float r = rd[tid];
      p1 += r * wg_w[NH + tid];
      p2 += r * dmd_w[NH + tid];
    }
    #pragma unroll
    for (int off = 1; off < 64; off <<= 1) {
      p1 += __shfl_xor(p1, off);
      p2 += __shfl_xor(p2, off);
      p3 += __shfl_xor(p3, off);
    }
    if (lane == 0) { gred[wv] = p1; gred[8 + wv] = p2; gred[16 + wv] = p3; }
  }
  {
    const int d = tid & 127, p = tid >> 7;
    const float* W = wv_w + (size_t)(p * 256) * ND + d;
    const float* L = lat + p * 256;
    float acc = 0.f;
    #pragma unroll 8
    for (int h = 0; h < 256; ++h) acc = fmaf(L[h], W[(size_t)h * ND], acc);
    part[tid] = acc;
  }
  __syncthreads();

  // ---- I2: gate scalar ----
  if (tid == 0) {
    float z1 = wg_b[0], z2 = dmd_b[0], z3 = ph_b[0];
    #pragma unroll
    for (int k = 0; k < 8; ++k) { z1 += gred[k]; z2 += gred[8 + k]; z3 += gred[16 + k]; }
    float g  = 1.f / (1.f + expf(-z1));
    float dm = tanhf(z2);
    g = g * (0.75f + 0.25f * (dm + 1.f));
    g = fminf(fmaxf(g, 0.f), 1.f);
    g = g * (0.5f * (1.f + cosf(z3)));
    scal[0] = g;
  }
  __syncthreads();

  // ---- J: outputs: weights, gate-scaled weights, value vector ----
  {
    const float g = scal[0];
    float w0 = wfull[tid], w1 = wfull[tid + 512];
    out_wts[(size_t)b * NS + tid]       = w0;
    out_wts[(size_t)b * NS + tid + 512] = w1;
    gw_out [(size_t)b * NS + tid]       = g * w0;
    gw_out [(size_t)b * NS + tid + 512] = g * w1;
    if (tid < ND)
      valw[(size_t)b * ND + tid] =
          part[tid] + part[tid + 128] + part[tid + 256] + part[tid + 384] + wv_b[tid];
  }
}

// ---------------- Kernel 2: bulk copy + sparse blend (streaming) -----------
__global__ __launch_bounds__(256) void copy_blend_kernel(
    const float* __restrict__ memory,   // [B,S,D]
    const float* __restrict__ gw,       // [B,S] gate*weight (mostly zero)
    const float* __restrict__ valw,     // [B,D]
    float* __restrict__ out_mem)        // [B,S,D]
{
  // 2^24 float4 total / (8192*256 threads) = exactly 8 float4 per thread
  const size_t t = (size_t)blockIdx.x * 256 + threadIdx.x;
  const size_t stride = (size_t)8192 * 256;
  #pragma unroll
  for (int j = 0; j < 8; ++j) {
    size_t i = t + (size_t)j * stride;          // float4 index
    fx4 m = __builtin_nontemporal_load((const fx4*)memory + i);
    int row = (int)(i >> 5);                    // b*S + s  (32 float4 per row)
    float wgt = gw[row];
    fx4 o = m;
    if (wgt != 0.f) {                           // 32/1024 rows per batch
      float omw = 1.f - wgt;
      const fx4 v = *((const fx4*)valw + (size_t)((row >> 10) << 5) + (i & 31));
      o = omw * m + wgt * v;
    }
    __builtin_nontemporal_store(o, (fx4*)out_mem + i);
  }
}

extern "C" void kernel_launch(void* const* d_in, const int* in_sizes, int n_in,
                              void* d_out, int out_size, void* d_ws, size_t ws_size,
                              hipStream_t stream) {
  const float* latent  = (const float*)d_in[0];
  const float* memory  = (const float*)d_in[1];
  const float* rq_w    = (const float*)d_in[2];
  const float* rq_b    = (const float*)d_in[3];
  const float* mem_key = (const float*)d_in[4];
  const float* wg_w    = (const float*)d_in[5];
  const float* wg_b    = (const float*)d_in[6];
  const float* dmd_w   = (const float*)d_in[7];
  const float* dmd_b   = (const float*)d_in[8];
  const float* ph_w    = (const float*)d_in[9];
  const float* ph_b    = (const float*)d_in[10];
  const float* wv_w    = (const float*)d_in[11];
  const float* wv_b    = (const float*)d_in[12];

  float* out_read = (float*)d_out;                          // [B,D]
  float* out_mem  = out_read + (size_t)NB * ND;             // [B,S,D]
  float* out_wts  = out_mem + (size_t)NB * NS * ND;         // [B,S]

  float* gw   = (float*)d_ws;                               // [B,S]
  float* valw = gw + (size_t)NB * NS;                       // [B,D]

  compute_kernel<<<NB, 512, 0, stream>>>(
      latent, memory, rq_w, rq_b, mem_key, wg_w, wg_b, dmd_w, dmd_b,
      ph_w, ph_b, wv_w, wv_b, out_read, out_wts, gw, valw);

  copy_blend_kernel<<<8192, 256, 0, stream>>>(memory, gw, valw, out_mem);
}